// Round 1
// baseline (290.503 us; speedup 1.0000x reference)
//
#include <hip/hip_runtime.h>

// Attention_32822140076224  (B=2,H=8,S=2048,D=64, fp32 in/out, int32 mask)
//   a = QK^T/8 ; a = where(mask, -1e9, a) ; p = softmax(a) ; o = a @ V (source bug: raw a)
// Strategy: per workgroup = (bh, 16 q-rows) x all 2048 k.
//   - scores^T via mfma_f32_16x16x16f16 (A=K, B=Q^T)  -> lane holds (k=kb+4g+r, q=q0+ql)
//   - that D-fragment is exactly the A-fragment of mfma_f32_16x16x16bf16_1k for o = a@V
//   - scores kept packed f16 in 64 VGPRs/lane (clamped at -60000 so f16 finite; exp->0 same)
//   - mask int32 read nontemporal (268 MB), P written nontemporal (268 MB): HBM-bound ~90us floor

#define SS   2048
#define DD   64
#define QB   16
#define NT   32      // k-tiles per wave (4 waves x 32 x 16 = 2048)

typedef _Float16 half4_t  __attribute__((ext_vector_type(4)));
typedef _Float16 half2_t  __attribute__((ext_vector_type(2)));
typedef short    short4_t __attribute__((ext_vector_type(4)));
typedef float    float4_t __attribute__((ext_vector_type(4)));
typedef int      int4_t   __attribute__((ext_vector_type(4)));

static __device__ __forceinline__ short f2bf(float f) {
  union { float f; unsigned u; } c; c.f = f;
  return (short)((c.u + 0x7fffu + ((c.u >> 16) & 1u)) >> 16);
}
static __device__ __forceinline__ unsigned packh2(float a, float b) {
  union { half2_t h; unsigned u; } c;
  c.h.x = (_Float16)a; c.h.y = (_Float16)b;
  return c.u;
}
static __device__ __forceinline__ void unpackh2(unsigned u, float& a, float& b) {
  union { unsigned u; half2_t h; } c; c.u = u;
  a = (float)c.h.x; b = (float)c.h.y;
}

extern "C" __global__ __launch_bounds__(256, 2)
void attn_fused_k(const float* __restrict__ Qg, const float* __restrict__ Kg,
                  const float* __restrict__ Vg, const int* __restrict__ Mg,
                  float* __restrict__ Og, float* __restrict__ Pg)
{
  __shared__ float ored[4][QB][DD];   // per-wave O partials (16 KB)
  __shared__ float redm[4][16];
  __shared__ float redz[4][16];

  // XCD-aware swizzle: XCD x (= blockIdx%8) owns heads {2x, 2x+1} -> K/V L2-resident
  const int wg  = blockIdx.x;
  const int xcd = wg & 7;
  const int ii  = wg >> 3;            // 0..255
  const int bh  = 2 * xcd + (ii >> 7);
  const int q0  = (ii & 127) * QB;

  const int tid  = threadIdx.x;
  const int w    = tid >> 6;          // wave 0..3
  const int lane = tid & 63;
  const int g    = lane >> 4;         // 0..3
  const int ql   = lane & 15;         // q-col within tile / d-col / k-row

  const float* Qb = Qg + ((size_t)bh * SS + q0 + ql) * DD;
  const float* Kb = Kg + (size_t)bh * SS * DD;
  const float* Vb = Vg + (size_t)bh * SS * DD;
  const int*   Mb = Mg + ((size_t)bh * SS + q0 + ql) * SS;
  float*       Pb = Pg + ((size_t)bh * SS + q0 + ql) * SS;

  // Q B-fragments: qf[c][j] = (f16) Q[q0+ql][16c + 4g + j]
  half4_t qf[4];
  #pragma unroll
  for (int c = 0; c < 4; ++c) {
    float4_t t = *(const float4_t*)(Qb + 16 * c + 4 * g);
    half4_t h; h.x=(_Float16)t.x; h.y=(_Float16)t.y; h.z=(_Float16)t.z; h.w=(_Float16)t.w;
    qf[c] = h;
  }

  float4_t accO[4];
  #pragma unroll
  for (int c = 0; c < 4; ++c) accO[c] = (float4_t){0.f, 0.f, 0.f, 0.f};
  float rmax = -60000.f;
  unsigned sreg[NT][2];

  // mask prefetch, 4 tiles deep (keeps ~4 KB/wave in flight for HBM latency)
  int4_t mbuf[4];
  #pragma unroll
  for (int p = 0; p < 4; ++p) {
    const int kb = 64 * p + 16 * w;
    mbuf[p] = __builtin_nontemporal_load((const int4_t*)(Mb + kb + 4 * g));
  }

  #pragma unroll
  for (int i = 0; i < NT; ++i) {
    const int kb = 64 * i + 16 * w;   // waves interleaved: adjacent tiles concurrent

    // K A-fragments: kf[c][j] = (f16) K[kb+ql][16c + 4g + j]
    half4_t kf[4];
    #pragma unroll
    for (int c = 0; c < 4; ++c) {
      float4_t t = *(const float4_t*)(Kb + (size_t)(kb + ql) * DD + 16 * c + 4 * g);
      half4_t h; h.x=(_Float16)t.x; h.y=(_Float16)t.y; h.z=(_Float16)t.z; h.w=(_Float16)t.w;
      kf[c] = h;
    }

    // V B-fragments (scalar f32 gathers; L1/L2-hot, V tile reused by all 4 waves)
    float vtmp[4][4];
    #pragma unroll
    for (int c = 0; c < 4; ++c)
      #pragma unroll
      for (int j = 0; j < 4; ++j)
        vtmp[c][j] = Vb[(size_t)(kb + 4 * g + j) * DD + 16 * c + ql];

    // scores^T tile: D[k_local][q] ; lane -> (k = kb+4g+r, q = q0+ql)
    float4_t acc = (float4_t){0.f, 0.f, 0.f, 0.f};
    #pragma unroll
    for (int c = 0; c < 4; ++c)
      acc = __builtin_amdgcn_mfma_f32_16x16x16f16(kf[c], qf[c], acc, 0, 0, 0);

    const int4_t m4 = mbuf[i & 3];
    if (i + 4 < NT) {
      const int kb2 = 64 * (i + 4) + 16 * w;
      mbuf[i & 3] = __builtin_nontemporal_load((const int4_t*)(Mb + kb2 + 4 * g));
    }

    float a0 = m4.x ? -1e9f : acc.x * 0.125f;
    float a1 = m4.y ? -1e9f : acc.y * 0.125f;
    float a2 = m4.z ? -1e9f : acc.z * 0.125f;
    float a3 = m4.w ? -1e9f : acc.w * 0.125f;

    // clamp for f16 storage (exp(-60000-m) == 0 same as -1e9; all-masked row still matches ref)
    const float c0 = fmaxf(a0, -60000.f), c1 = fmaxf(a1, -60000.f);
    const float c2 = fmaxf(a2, -60000.f), c3 = fmaxf(a3, -60000.f);
    rmax = fmaxf(rmax, fmaxf(fmaxf(c0, c1), fmaxf(c2, c3)));
    sreg[i][0] = packh2(c0, c1);
    sreg[i][1] = packh2(c2, c3);

    // o += a @ V  (bf16: holds -1e9 with 0.18% rounding; budget is 3e9 absmax)
    short4_t af; af.x = f2bf(a0); af.y = f2bf(a1); af.z = f2bf(a2); af.w = f2bf(a3);
    #pragma unroll
    for (int c = 0; c < 4; ++c) {
      short4_t vf; vf.x = f2bf(vtmp[c][0]); vf.y = f2bf(vtmp[c][1]);
                   vf.z = f2bf(vtmp[c][2]); vf.w = f2bf(vtmp[c][3]);
      accO[c] = __builtin_amdgcn_mfma_f32_16x16x16bf16_1k(af, vf, accO[c], 0, 0, 0);
    }
  }

  // row max: lanes {ql, ql+16, ql+32, ql+48} hold the same q-row
  rmax = fmaxf(rmax, __shfl_xor(rmax, 16));
  rmax = fmaxf(rmax, __shfl_xor(rmax, 32));

  // O partials -> LDS ; per-wave row max -> LDS
  #pragma unroll
  for (int c = 0; c < 4; ++c) {
    ored[w][4 * g + 0][16 * c + ql] = accO[c].x;
    ored[w][4 * g + 1][16 * c + ql] = accO[c].y;
    ored[w][4 * g + 2][16 * c + ql] = accO[c].z;
    ored[w][4 * g + 3][16 * c + ql] = accO[c].w;
  }
  if (lane < 16) redm[w][ql] = rmax;
  __syncthreads();

  const float m = fmaxf(fmaxf(redm[0][ql], redm[1][ql]),
                        fmaxf(redm[2][ql], redm[3][ql]));

  // O cross-wave reduce + coalesced store (all 256 threads)
  {
    const int row = tid >> 4;
    const int col = (tid & 15) * 4;
    float4_t s0 = *(const float4_t*)&ored[0][row][col];
    float4_t s1 = *(const float4_t*)&ored[1][row][col];
    float4_t s2 = *(const float4_t*)&ored[2][row][col];
    float4_t s3 = *(const float4_t*)&ored[3][row][col];
    float4_t s;
    s.x = (s0.x + s1.x) + (s2.x + s3.x);
    s.y = (s0.y + s1.y) + (s2.y + s3.y);
    s.z = (s0.z + s1.z) + (s2.z + s3.z);
    s.w = (s0.w + s1.w) + (s2.w + s3.w);
    *(float4_t*)(Og + ((size_t)bh * SS + q0 + row) * DD + col) = s;
  }

  // pass 2: e = exp(a - m), row sum
  float zs = 0.f;
  #pragma unroll
  for (int i = 0; i < NT; ++i) {
    float a0, a1, a2, a3;
    unpackh2(sreg[i][0], a0, a1);
    unpackh2(sreg[i][1], a2, a3);
    const float e0 = __expf(a0 - m), e1 = __expf(a1 - m);
    const float e2 = __expf(a2 - m), e3 = __expf(a3 - m);
    zs += (e0 + e1) + (e2 + e3);
    sreg[i][0] = packh2(e0, e1);
    sreg[i][1] = packh2(e2, e3);
  }
  zs += __shfl_xor(zs, 16);
  zs += __shfl_xor(zs, 32);
  if (lane < 16) redz[w][ql] = zs;
  __syncthreads();
  const float Z    = (redz[0][ql] + redz[1][ql]) + (redz[2][ql] + redz[3][ql]);
  const float invZ = 1.0f / Z;

  // pass 3: P writes (nontemporal dwordx4, full 64B lines per 16-lane group)
  #pragma unroll
  for (int i = 0; i < NT; ++i) {
    const int kb = 64 * i + 16 * w;
    float e0, e1, e2, e3;
    unpackh2(sreg[i][0], e0, e1);
    unpackh2(sreg[i][1], e2, e3);
    float4_t pv;
    pv.x = e0 * invZ; pv.y = e1 * invZ; pv.z = e2 * invZ; pv.w = e3 * invZ;
    __builtin_nontemporal_store(pv, (float4_t*)(Pb + kb + 4 * g));
  }
}

extern "C" void kernel_launch(void* const* d_in, const int* in_sizes, int n_in,
                              void* d_out, int out_size, void* d_ws, size_t ws_size,
                              hipStream_t stream) {
  const float* Q = (const float*)d_in[0];
  const float* K = (const float*)d_in[1];
  const float* V = (const float*)d_in[2];
  const int*   M = (const int*)d_in[3];   // bool mask staged as int32 per harness contract
  float* Ov = (float*)d_out;                                   // attn_v: 2*8*2048*64
  float* P  = (float*)d_out + (size_t)2 * 8 * 2048 * 64;       // attn_p: 2*8*2048*2048
  attn_fused_k<<<dim3(2048), dim3(256), 0, stream>>>(Q, K, V, M, Ov, P);
}